// Round 8
// baseline (448.990 us; speedup 1.0000x reference)
//
#include <hip/hip_runtime.h>

#define B_ 2
#define L_ 2048
#define D_ 512
#define H_ 8
#define S_ 2048

typedef __attribute__((ext_vector_type(8))) short short8;
typedef __attribute__((ext_vector_type(8))) unsigned short ushort8;
typedef __attribute__((ext_vector_type(4))) unsigned short ushort4v;
typedef __attribute__((ext_vector_type(4))) float f32x4;
typedef __attribute__((ext_vector_type(16))) float f32x16;
typedef __attribute__((ext_vector_type(4))) float float4v;

__device__ __forceinline__ unsigned short f2bf(float f) {
    unsigned u = __float_as_uint(f);
    u += 0x7FFF + ((u >> 16) & 1);   // RTNE
    return (unsigned short)(u >> 16);
}
__device__ __forceinline__ float bf2f(unsigned short s) {
    return __uint_as_float(((unsigned)s) << 16);
}
// swap bits 2 and 3 (self-inverse) — K-row permutation making S^T C-regs = PV B-frag order
__device__ __forceinline__ int swap23(int x) {
    return (x & ~12) | ((x & 4) << 1) | ((x & 8) >> 1);
}
// async global->LDS, 16B per lane; LDS dest = uniform base + lane*16
__device__ __forceinline__ void async16(void* lds, const void* g) {
    __builtin_amdgcn_global_load_lds(
        (const __attribute__((address_space(1))) void*)(g),
        (__attribute__((address_space(3))) void*)(lds), 16, 0, 0);
}

// ---------------- fused fp32->bf16 converts: x (524288 f4) + 4 weights (65536 f4 each) ----------------
__global__ __launch_bounds__(256) void cvt_all(const float* __restrict__ x,
                                               const float* __restrict__ w0, const float* __restrict__ w1,
                                               const float* __restrict__ w2, const float* __restrict__ w3,
                                               unsigned short* __restrict__ xb,
                                               unsigned short* __restrict__ d0, unsigned short* __restrict__ d1,
                                               unsigned short* __restrict__ d2, unsigned short* __restrict__ d3) {
    int i = blockIdx.x * 256 + threadIdx.x;   // [0, 786432)
    const float* s;
    unsigned short* d;
    int idx;
    if (i < 524288) { s = x; d = xb; idx = i; }
    else {
        int off = i - 524288;                  // [0, 262144): 4 weights x 65536 float4
        int wsel = off >> 16; idx = off & 65535;
        s = (wsel == 0) ? w0 : (wsel == 1) ? w1 : (wsel == 2) ? w2 : w3;
        d = (wsel == 0) ? d0 : (wsel == 1) ? d1 : (wsel == 2) ? d2 : d3;
    }
    float4v v = *(const float4v*)(s + (size_t)idx * 4);
    ushort4v o;
    o[0] = f2bf(v[0]); o[1] = f2bf(v[1]); o[2] = f2bf(v[2]); o[3] = f2bf(v[3]);
    *(ushort4v*)(d + (size_t)idx * 4) = o;
}

// ---------------- content bias (PRE-SCALED by 1/8): cb'[b,h,s] = dot(x,Wb)/8 ----------------
__global__ __launch_bounds__(256) void cb_kernel(const float* __restrict__ x,
                                                 const float* __restrict__ Wb,
                                                 float* __restrict__ cb) {
    const int tid = threadIdx.x, w = tid >> 6, lane = tid & 63;
    const int row = blockIdx.x * 4 + w;            // [0, 4096)
    const int h = lane >> 3, seg = lane & 7;
    const float* xp = x + (size_t)row * 512 + seg * 64;
    const float* wp = Wb + (size_t)h * 512 + seg * 64;
    float acc = 0.f;
    #pragma unroll
    for (int j = 0; j < 16; ++j) {
        float4v xv = *(const float4v*)(xp + j * 4);
        float4v wv = *(const float4v*)(wp + j * 4);
        acc += xv[0] * wv[0] + xv[1] * wv[1] + xv[2] * wv[2] + xv[3] * wv[3];
    }
    acc += __shfl_xor(acc, 1);
    acc += __shfl_xor(acc, 2);
    acc += __shfl_xor(acc, 4);
    if (seg == 0) {
        int b = row >> 11, s = row & 2047;
        cb[((size_t)(b * H_ + h)) * S_ + s] = acc * 0.125f;
    }
}

// ---------------- 64x64-tile GEMM core ----------------
__device__ __forceinline__ void gemm64_core(const unsigned short* __restrict__ Ap,
                                            const unsigned short* __restrict__ Bp,
                                            short* sA, short* sB, int tid, f32x4 c[4]) {
    const int w = tid >> 6, lane = tid & 63, quad = lane >> 4, l15 = lane & 15;
    for (int kc = 0; kc < 8; ++kc) {
        __syncthreads();
        #pragma unroll
        for (int i = tid; i < 512; i += 256) {
            int row = i >> 3, seg = i & 7;
            *(ushort8*)&sA[row * 72 + seg * 8] = *(const ushort8*)(Ap + (size_t)row * 512 + kc * 64 + seg * 8);
            *(ushort8*)&sB[row * 72 + seg * 8] = *(const ushort8*)(Bp + (size_t)row * 512 + kc * 64 + seg * 8);
        }
        __syncthreads();
        #pragma unroll
        for (int ks = 0; ks < 2; ++ks) {
            short8 a = *(const short8*)&sA[(w * 16 + l15) * 72 + ks * 32 + quad * 8];
            #pragma unroll
            for (int jj = 0; jj < 4; ++jj) {
                short8 b = *(const short8*)&sB[(jj * 16 + l15) * 72 + ks * 32 + quad * 8];
                c[jj] = __builtin_amdgcn_mfma_f32_16x16x32_bf16(a, b, c[jj], 0, 0, 0);
            }
        }
    }
}

// ---------------- q,k,v projections ----------------
// q: row-major bf16.
// K: A-frag packed for 32x32x16, rows sigma-permuted:
//    addr = ((b*64 + (s>>5))*32 + (d>>4))*512 + ((d>>3)&1)*256 + swap23(s&31)*8 + (d&7)
// V: transposed row-major vt[b][h][dh][s]
__global__ __launch_bounds__(256) void gemm_qkv(const unsigned short* __restrict__ xb,
                                                const unsigned short* __restrict__ Wqb,
                                                const unsigned short* __restrict__ Wkb,
                                                const unsigned short* __restrict__ Wvb,
                                                unsigned short* __restrict__ qb,
                                                unsigned short* __restrict__ kpack,
                                                unsigned short* __restrict__ vt) {
    __shared__ short sA[64 * 72];
    __shared__ short sB[64 * 72];
    const int m0 = blockIdx.x * 64, n0 = blockIdx.y * 64, z = blockIdx.z;
    const unsigned short* Bsel = (z == 0) ? Wqb : ((z == 1) ? Wkb : Wvb);
    f32x4 c[4];
    #pragma unroll
    for (int jj = 0; jj < 4; ++jj) { f32x4 zv = {0.f, 0.f, 0.f, 0.f}; c[jj] = zv; }
    gemm64_core(xb + (size_t)m0 * 512, Bsel + (size_t)n0 * 512, sA, sB, threadIdx.x, c);
    const int tid = threadIdx.x, w = tid >> 6, lane = tid & 63, quad = lane >> 4, l15 = lane & 15;
    const int mbase = m0 + w * 16 + quad * 4;
    const int bb = mbase >> 11;
    if (z == 0) {
        #pragma unroll
        for (int jj = 0; jj < 4; ++jj)
            #pragma unroll
            for (int r = 0; r < 4; ++r)
                qb[(size_t)(mbase + r) * 512 + n0 + jj * 16 + l15] = f2bf(c[jj][r]);
    } else if (z == 1) {
        #pragma unroll
        for (int jj = 0; jj < 4; ++jj) {
            int d = n0 + jj * 16 + l15;
            int f = d >> 4, hid = (d >> 3) & 1, j = d & 7;
            #pragma unroll
            for (int r = 0; r < 4; ++r) {
                int s = (mbase + r) & 2047;
                int t = s >> 5, rr = swap23(s & 31);
                kpack[(((size_t)(bb * 64 + t)) * 32 + f) * 512 + hid * 256 + rr * 8 + j]
                    = f2bf(c[jj][r]);
            }
        }
    } else {
        const int hh = n0 >> 6;
        const int s = mbase & 2047;
        #pragma unroll
        for (int jj = 0; jj < 4; ++jj) {
            int dh = (n0 & 63) + jj * 16 + l15;
            ushort4v o;
            o[0] = f2bf(c[jj][0]); o[1] = f2bf(c[jj][1]);
            o[2] = f2bf(c[jj][2]); o[3] = f2bf(c[jj][3]);
            *(ushort4v*)(vt + (((size_t)(bb * H_ + hh) * 64 + dh) * S_ + s)) = o;
        }
    }
}

// ---------------- output projection (fp32 out + bias) ----------------
__global__ __launch_bounds__(256) void gemm_out(const unsigned short* __restrict__ ctxb,
                                                const unsigned short* __restrict__ Wdb,
                                                const float* __restrict__ bd,
                                                float* __restrict__ out) {
    __shared__ short sA[64 * 72];
    __shared__ short sB[64 * 72];
    const int m0 = blockIdx.x * 64, n0 = blockIdx.y * 64;
    f32x4 c[4];
    #pragma unroll
    for (int jj = 0; jj < 4; ++jj) { f32x4 zv = {0.f, 0.f, 0.f, 0.f}; c[jj] = zv; }
    gemm64_core(ctxb + (size_t)m0 * 512, Wdb + (size_t)n0 * 512, sA, sB, threadIdx.x, c);
    const int tid = threadIdx.x, w = tid >> 6, lane = tid & 63, quad = lane >> 4, l15 = lane & 15;
    #pragma unroll
    for (int jj = 0; jj < 4; ++jj) {
        float bias = bd[n0 + jj * 16 + l15];
        #pragma unroll
        for (int r = 0; r < 4; ++r)
            out[(size_t)(m0 + w * 16 + quad * 4 + r) * 512 + n0 + jj * 16 + l15] = c[jj][r] + bias;
    }
}

// ---------------- flash attention v7b: S^T + async LDS staging + split-S x4 ----------------
// bid bits: [0..1]=quarter, [2]=b, [3..5]=h, [6..9]=qt. 16 S-tiles of 32 per block.
__global__ __launch_bounds__(256, 3) void flash_attn(const unsigned short* __restrict__ qb,
                                                     const unsigned short* __restrict__ kpack,
                                                     const unsigned short* __restrict__ vt,
                                                     const float* __restrict__ cb_all,
                                                     const float* __restrict__ mixing,
                                                     _Float16* __restrict__ Opart,
                                                     float* __restrict__ lpart) {
    __shared__ short sK[2][8192];     // 2 x 16 KB (one 32s x 256d chunk each)
    __shared__ short sV[2048];        // 4 KB, frag-major (4 frags x 512 shorts)
    const int bid = blockIdx.x;
    const int quarter = bid & 3, b = (bid >> 2) & 1, h = (bid >> 3) & 7, qt = bid >> 6;
    const int tid = threadIdx.x, w = tid >> 6, lane = tid & 63;
    const int l31 = lane & 31, hi = lane >> 5;
    const int q0 = qt * 128 + w * 32;
    const unsigned short* kbase = kpack + ((size_t)(b * 64 + quarter * 16)) * 32 * 512;
    const unsigned short* vtb = vt + ((size_t)(b * H_ + h) * 64) * (size_t)S_;
    const float* cbp = cb_all + (size_t)(b * H_ + h) * S_ + quarter * 512;
    const float* mixh = mixing + h * D_;

    // ---- Q B-frags (n=q=l31, k=d), mixing folded ----
    short8 qf[32];
    {
        const unsigned short* qrow = qb + ((size_t)(b * L_) + q0 + l31) * D_ + hi * 8;
        #pragma unroll
        for (int i = 0; i < 32; ++i) {
            ushort8 qv = *(const ushort8*)(qrow + i * 16);
            float4v ma = *(const float4v*)(mixh + i * 16 + hi * 8);
            float4v mb = *(const float4v*)(mixh + i * 16 + hi * 8 + 4);
            short8 ov;
            ov[0] = (short)f2bf(bf2f(qv[0]) * ma[0]);
            ov[1] = (short)f2bf(bf2f(qv[1]) * ma[1]);
            ov[2] = (short)f2bf(bf2f(qv[2]) * ma[2]);
            ov[3] = (short)f2bf(bf2f(qv[3]) * ma[3]);
            ov[4] = (short)f2bf(bf2f(qv[4]) * mb[0]);
            ov[5] = (short)f2bf(bf2f(qv[5]) * mb[1]);
            ov[6] = (short)f2bf(bf2f(qv[6]) * mb[2]);
            ov[7] = (short)f2bf(bf2f(qv[7]) * mb[3]);
            qf[i] = ov;
        }
    }

    f32x16 acco0, acco1;
    #pragma unroll
    for (int i = 0; i < 16; ++i) { acco0[i] = 0.f; acco1[i] = 0.f; }
    float lsum = 0.f;

    // ---- prologue: async-stage tile0 chunk0 -> buf0 ----
    #pragma unroll
    for (int ii = 0; ii < 4; ++ii)
        async16((char*)&sK[0][0] + w * 1024 + ii * 4096,
                (const char*)kbase + w * 1024 + ii * 4096 + (size_t)lane * 16);
    __syncthreads();

    for (int t = 0; t < 16; ++t) {
        f32x16 accsA, accsB;
        #pragma unroll
        for (int i = 0; i < 16; ++i) { accsA[i] = 0.f; accsB[i] = 0.f; }

        // ======== Phase A: issue chunk1 + V loads, compute chunk0 ========
        {
            const char* src = (const char*)(kbase + ((size_t)t * 32 + 16) * 512);
            #pragma unroll
            for (int ii = 0; ii < 4; ++ii)
                async16((char*)&sK[1][0] + w * 1024 + ii * 4096,
                        src + w * 1024 + ii * 4096 + (size_t)lane * 16);
            // V frag F=w: dhg=w>>1, sgi=w&1; lane (l31,hi) -> (dh=dhg*32+l31, s=t*32+sgi*16+hi*8)
            const unsigned short* gv = vtb + ((size_t)((w >> 1) * 32 + l31)) * (size_t)S_
                                       + quarter * 512 + t * 32 + (w & 1) * 16 + hi * 8;
            async16((char*)&sV[0] + w * 1024, gv);
        }
        #pragma unroll
        for (int f = 0; f < 16; ++f) {
            short8 a = *(const short8*)&sK[0][f * 512 + lane * 8];
            if (f & 1) accsB = __builtin_amdgcn_mfma_f32_32x32x16_bf16(a, qf[f], accsB, 0, 0, 0);
            else       accsA = __builtin_amdgcn_mfma_f32_32x32x16_bf16(a, qf[f], accsA, 0, 0, 0);
        }
        __syncthreads();   // drains async loads (vmcnt), protects buffers

        // ======== Phase B: issue next tile chunk0, compute chunk1, softmax, PV ========
        if (t < 15) {
            const char* src = (const char*)(kbase + ((size_t)(t + 1) * 32) * 512);
            #pragma unroll
            for (int ii = 0; ii < 4; ++ii)
                async16((char*)&sK[0][0] + w * 1024 + ii * 4096,
                        src + w * 1024 + ii * 4096 + (size_t)lane * 16);
        }
        #pragma unroll
        for (int f = 0; f < 16; ++f) {
            short8 a = *(const short8*)&sK[1][f * 512 + lane * 8];
            if (f & 1) accsB = __builtin_amdgcn_mfma_f32_32x32x16_bf16(a, qf[16 + f], accsB, 0, 0, 0);
            else       accsA = __builtin_amdgcn_mfma_f32_32x32x16_bf16(a, qf[16 + f], accsA, 0, 0, 0);
        }

        // ---- softmax numerator (no max; cb pre-scaled by 1/8) ----
        const int s0 = t * 32;
        float p[16];
        #pragma unroll
        for (int R = 0; R < 16; ++R) {
            const int cr = (R & 3) + 8 * (R >> 2);
            const int idx = s0 + cr - 4 * ((R >> 2) & 1);
            float cbA = cbp[idx];
            float cbB = cbp[idx + 8];
            float cbv = hi ? cbB : cbA;
            float pe = __expf((accsA[R] + accsB[R]) * 0.125f + cbv);
            p[R] = pe;
            lsum += pe;
        }
        // ---- pack P -> bf16 B-frags via +0x8000 (RN) + v_perm ----
        union { unsigned int u[4]; short8 s8; } P0, P1;
        #pragma unroll
        for (int j = 0; j < 4; ++j) {
            P0.u[j] = __builtin_amdgcn_perm(__float_as_uint(p[2 * j + 1]) + 0x8000u,
                                            __float_as_uint(p[2 * j]) + 0x8000u, 0x07060302u);
            P1.u[j] = __builtin_amdgcn_perm(__float_as_uint(p[8 + 2 * j + 1]) + 0x8000u,
                                            __float_as_uint(p[8 + 2 * j]) + 0x8000u, 0x07060302u);
        }
        // ---- O^T += V^T P^T ----
        {
            short8 av00 = *(const short8*)&sV[0 * 512 + lane * 8];
            short8 av01 = *(const short8*)&sV[1 * 512 + lane * 8];
            short8 av10 = *(const short8*)&sV[2 * 512 + lane * 8];
            short8 av11 = *(const short8*)&sV[3 * 512 + lane * 8];
            acco0 = __builtin_amdgcn_mfma_f32_32x32x16_bf16(av00, P0.s8, acco0, 0, 0, 0);
            acco0 = __builtin_amdgcn_mfma_f32_32x32x16_bf16(av01, P1.s8, acco0, 0, 0, 0);
            acco1 = __builtin_amdgcn_mfma_f32_32x32x16_bf16(av10, P0.s8, acco1, 0, 0, 0);
            acco1 = __builtin_amdgcn_mfma_f32_32x32x16_bf16(av11, P1.s8, acco1, 0, 0, 0);
        }
        __syncthreads();   // drains next-chunk0 load; protects sV/sK[0] for next tile
    }

    // ---- epilogue: lsum merge, fp16 O^T partials ----
    lsum += __shfl_xor(lsum, 32);
    if (hi == 0) lpart[(size_t)bid * 128 + w * 32 + l31] = lsum;
    #pragma unroll
    for (int R = 0; R < 16; ++R) {
        int dh = (R & 3) + 8 * (R >> 2) + 4 * hi;
        Opart[((size_t)bid * 64 + dh) * 128 + w * 32 + l31] = (_Float16)acco0[R];
        Opart[((size_t)bid * 64 + 32 + dh) * 128 + w * 32 + l31] = (_Float16)acco1[R];
    }
}

// ---------------- merge 4 split-S partials -> ctx (bf16) ----------------
__global__ __launch_bounds__(256) void merge_ctx(const _Float16* __restrict__ Opart,
                                                 const float* __restrict__ lpart,
                                                 unsigned short* __restrict__ ctxb) {
    int t = blockIdx.x * 256 + threadIdx.x;       // [0, 524288)
    int qq = t & 127, dh4 = (t >> 7) & 15, qt = (t >> 11) & 15, h = (t >> 15) & 7, b = t >> 18;
    int base = (qt << 6) | (h << 3) | (b << 2);   // flash bid with quarter=0
    float l = 0.f;
    #pragma unroll
    for (int p = 0; p < 4; ++p) l += lpart[(size_t)(base + p) * 128 + qq];
    float inv = 1.f / l;
    ushort4v o;
    #pragma unroll
    for (int e = 0; e < 4; ++e) {
        int dh = dh4 * 4 + e;
        float v = 0.f;
        #pragma unroll
        for (int p = 0; p < 4; ++p)
            v += (float)Opart[((size_t)(base + p) * 64 + dh) * 128 + qq];
        o[e] = f2bf(v * inv);
    }
    *(ushort4v*)(ctxb + ((size_t)(b * L_) + qt * 128 + qq) * 512 + h * 64 + dh4 * 4) = o;
}

extern "C" void kernel_launch(void* const* d_in, const int* in_sizes, int n_in,
                              void* d_out, int out_size, void* d_ws, size_t ws_size,
                              hipStream_t stream) {
    (void)in_sizes; (void)n_in; (void)out_size; (void)ws_size;
    const float* x      = (const float*)d_in[0];
    const float* Wq     = (const float*)d_in[1];
    const float* Wk     = (const float*)d_in[2];
    const float* Wv     = (const float*)d_in[3];
    const float* Wb     = (const float*)d_in[4];
    const float* mixing = (const float*)d_in[5];
    const float* Wd     = (const float*)d_in[6];
    const float* bd     = (const float*)d_in[7];
    float* out = (float*)d_out;

    char* ws = (char*)d_ws;
    const size_t MiB = 1048576;
    unsigned short* xb    = (unsigned short*)(ws);
    unsigned short* qb    = (unsigned short*)(ws + 4 * MiB);
    unsigned short* kpack = (unsigned short*)(ws + 8 * MiB);
    unsigned short* vt    = (unsigned short*)(ws + 12 * MiB);
    unsigned short* ctxb  = (unsigned short*)(ws + 16 * MiB);
    unsigned short* Wqb   = (unsigned short*)(ws + 20 * MiB);
    unsigned short* Wkb   = (unsigned short*)(ws + 20 * MiB + 512 * 1024);
    unsigned short* Wvb   = (unsigned short*)(ws + 21 * MiB);
    unsigned short* Wdb   = (unsigned short*)(ws + 21 * MiB + 512 * 1024);
    float* cbuf           = (float*)(ws + 22 * MiB);            // 128 KB
    float* lpart          = (float*)(ws + 23 * MiB);            // 512 KB
    _Float16* Opart       = (_Float16*)(ws + 24 * MiB);         // 16.78 MB

    cvt_all<<<3072, 256, 0, stream>>>(x, Wq, Wk, Wv, Wd, xb, Wqb, Wkb, Wvb, Wdb);
    gemm_qkv<<<dim3(64, 8, 3), 256, 0, stream>>>(xb, Wqb, Wkb, Wvb, qb, kpack, vt);
    cb_kernel<<<1024, 256, 0, stream>>>(x, Wb, cbuf);
    flash_attn<<<1024, 256, 0, stream>>>(qb, kpack, vt, cbuf, mixing, Opart, lpart);
    merge_ctx<<<2048, 256, 0, stream>>>(Opart, lpart, ctxb);
    gemm_out<<<dim3(64, 8), 256, 0, stream>>>(ctxb, Wdb, bd, out);
}

// Round 9
// 262.580 us; speedup vs baseline: 1.7099x; 1.7099x over previous
//
#include <hip/hip_runtime.h>

#define B_ 2
#define L_ 2048
#define D_ 512
#define H_ 8
#define S_ 2048

typedef __attribute__((ext_vector_type(8))) short short8;
typedef __attribute__((ext_vector_type(8))) unsigned short ushort8;
typedef __attribute__((ext_vector_type(4))) unsigned short ushort4v;
typedef __attribute__((ext_vector_type(4))) float f32x4;
typedef __attribute__((ext_vector_type(16))) float f32x16;
typedef __attribute__((ext_vector_type(4))) float float4v;

__device__ __forceinline__ unsigned short f2bf(float f) {
    unsigned u = __float_as_uint(f);
    u += 0x7FFF + ((u >> 16) & 1);   // RTNE
    return (unsigned short)(u >> 16);
}
__device__ __forceinline__ float bf2f(unsigned short s) {
    return __uint_as_float(((unsigned)s) << 16);
}
// swap bits 2 and 3 (self-inverse) — K-row permutation making S^T C-regs = PV B-frag order
__device__ __forceinline__ int swap23(int x) {
    return (x & ~12) | ((x & 4) << 1) | ((x & 8) >> 1);
}
// async global->LDS, 16B per lane; LDS dest = uniform base + lane*16
__device__ __forceinline__ void async16(void* lds, const void* g) {
    __builtin_amdgcn_global_load_lds(
        (const __attribute__((address_space(1))) void*)(g),
        (__attribute__((address_space(3))) void*)(lds), 16, 0, 0);
}

// ---------------- fused fp32->bf16 converts: x (524288 f4) + 4 weights (65536 f4 each) ----------------
__global__ __launch_bounds__(256) void cvt_all(const float* __restrict__ x,
                                               const float* __restrict__ w0, const float* __restrict__ w1,
                                               const float* __restrict__ w2, const float* __restrict__ w3,
                                               unsigned short* __restrict__ xb,
                                               unsigned short* __restrict__ d0, unsigned short* __restrict__ d1,
                                               unsigned short* __restrict__ d2, unsigned short* __restrict__ d3) {
    int i = blockIdx.x * 256 + threadIdx.x;   // [0, 786432)
    const float* s;
    unsigned short* d;
    int idx;
    if (i < 524288) { s = x; d = xb; idx = i; }
    else {
        int off = i - 524288;                  // [0, 262144): 4 weights x 65536 float4
        int wsel = off >> 16; idx = off & 65535;
        s = (wsel == 0) ? w0 : (wsel == 1) ? w1 : (wsel == 2) ? w2 : w3;
        d = (wsel == 0) ? d0 : (wsel == 1) ? d1 : (wsel == 2) ? d2 : d3;
    }
    float4v v = *(const float4v*)(s + (size_t)idx * 4);
    ushort4v o;
    o[0] = f2bf(v[0]); o[1] = f2bf(v[1]); o[2] = f2bf(v[2]); o[3] = f2bf(v[3]);
    *(ushort4v*)(d + (size_t)idx * 4) = o;
}

// ---------------- content bias (PRE-SCALED by 1/8): cb'[b,h,s] = dot(x,Wb)/8 ----------------
__global__ __launch_bounds__(256) void cb_kernel(const float* __restrict__ x,
                                                 const float* __restrict__ Wb,
                                                 float* __restrict__ cb) {
    const int tid = threadIdx.x, w = tid >> 6, lane = tid & 63;
    const int row = blockIdx.x * 4 + w;            // [0, 4096)
    const int h = lane >> 3, seg = lane & 7;
    const float* xp = x + (size_t)row * 512 + seg * 64;
    const float* wp = Wb + (size_t)h * 512 + seg * 64;
    float acc = 0.f;
    #pragma unroll
    for (int j = 0; j < 16; ++j) {
        float4v xv = *(const float4v*)(xp + j * 4);
        float4v wv = *(const float4v*)(wp + j * 4);
        acc += xv[0] * wv[0] + xv[1] * wv[1] + xv[2] * wv[2] + xv[3] * wv[3];
    }
    acc += __shfl_xor(acc, 1);
    acc += __shfl_xor(acc, 2);
    acc += __shfl_xor(acc, 4);
    if (seg == 0) {
        int b = row >> 11, s = row & 2047;
        cb[((size_t)(b * H_ + h)) * S_ + s] = acc * 0.125f;
    }
}

// ---------------- 64x64-tile GEMM core ----------------
__device__ __forceinline__ void gemm64_core(const unsigned short* __restrict__ Ap,
                                            const unsigned short* __restrict__ Bp,
                                            short* sA, short* sB, int tid, f32x4 c[4]) {
    const int w = tid >> 6, lane = tid & 63, quad = lane >> 4, l15 = lane & 15;
    for (int kc = 0; kc < 8; ++kc) {
        __syncthreads();
        #pragma unroll
        for (int i = tid; i < 512; i += 256) {
            int row = i >> 3, seg = i & 7;
            *(ushort8*)&sA[row * 72 + seg * 8] = *(const ushort8*)(Ap + (size_t)row * 512 + kc * 64 + seg * 8);
            *(ushort8*)&sB[row * 72 + seg * 8] = *(const ushort8*)(Bp + (size_t)row * 512 + kc * 64 + seg * 8);
        }
        __syncthreads();
        #pragma unroll
        for (int ks = 0; ks < 2; ++ks) {
            short8 a = *(const short8*)&sA[(w * 16 + l15) * 72 + ks * 32 + quad * 8];
            #pragma unroll
            for (int jj = 0; jj < 4; ++jj) {
                short8 b = *(const short8*)&sB[(jj * 16 + l15) * 72 + ks * 32 + quad * 8];
                c[jj] = __builtin_amdgcn_mfma_f32_16x16x32_bf16(a, b, c[jj], 0, 0, 0);
            }
        }
    }
}

// ---------------- q,k,v projections ----------------
// q: row-major bf16.
// K: A-frag packed for 32x32x16, rows sigma-permuted:
//    addr = ((b*64 + (s>>5))*32 + (d>>4))*512 + ((d>>3)&1)*256 + swap23(s&31)*8 + (d&7)
// V: transposed row-major vt[b][h][dh][s]
__global__ __launch_bounds__(256) void gemm_qkv(const unsigned short* __restrict__ xb,
                                                const unsigned short* __restrict__ Wqb,
                                                const unsigned short* __restrict__ Wkb,
                                                const unsigned short* __restrict__ Wvb,
                                                unsigned short* __restrict__ qb,
                                                unsigned short* __restrict__ kpack,
                                                unsigned short* __restrict__ vt) {
    __shared__ short sA[64 * 72];
    __shared__ short sB[64 * 72];
    const int m0 = blockIdx.x * 64, n0 = blockIdx.y * 64, z = blockIdx.z;
    const unsigned short* Bsel = (z == 0) ? Wqb : ((z == 1) ? Wkb : Wvb);
    f32x4 c[4];
    #pragma unroll
    for (int jj = 0; jj < 4; ++jj) { f32x4 zv = {0.f, 0.f, 0.f, 0.f}; c[jj] = zv; }
    gemm64_core(xb + (size_t)m0 * 512, Bsel + (size_t)n0 * 512, sA, sB, threadIdx.x, c);
    const int tid = threadIdx.x, w = tid >> 6, lane = tid & 63, quad = lane >> 4, l15 = lane & 15;
    const int mbase = m0 + w * 16 + quad * 4;
    const int bb = mbase >> 11;
    if (z == 0) {
        #pragma unroll
        for (int jj = 0; jj < 4; ++jj)
            #pragma unroll
            for (int r = 0; r < 4; ++r)
                qb[(size_t)(mbase + r) * 512 + n0 + jj * 16 + l15] = f2bf(c[jj][r]);
    } else if (z == 1) {
        #pragma unroll
        for (int jj = 0; jj < 4; ++jj) {
            int d = n0 + jj * 16 + l15;
            int f = d >> 4, hid = (d >> 3) & 1, j = d & 7;
            #pragma unroll
            for (int r = 0; r < 4; ++r) {
                int s = (mbase + r) & 2047;
                int t = s >> 5, rr = swap23(s & 31);
                kpack[(((size_t)(bb * 64 + t)) * 32 + f) * 512 + hid * 256 + rr * 8 + j]
                    = f2bf(c[jj][r]);
            }
        }
    } else {
        const int hh = n0 >> 6;
        const int s = mbase & 2047;
        #pragma unroll
        for (int jj = 0; jj < 4; ++jj) {
            int dh = (n0 & 63) + jj * 16 + l15;
            ushort4v o;
            o[0] = f2bf(c[jj][0]); o[1] = f2bf(c[jj][1]);
            o[2] = f2bf(c[jj][2]); o[3] = f2bf(c[jj][3]);
            *(ushort4v*)(vt + (((size_t)(bb * H_ + hh) * 64 + dh) * S_ + s)) = o;
        }
    }
}

// ---------------- output projection (fp32 out + bias) ----------------
__global__ __launch_bounds__(256) void gemm_out(const unsigned short* __restrict__ ctxb,
                                                const unsigned short* __restrict__ Wdb,
                                                const float* __restrict__ bd,
                                                float* __restrict__ out) {
    __shared__ short sA[64 * 72];
    __shared__ short sB[64 * 72];
    const int m0 = blockIdx.x * 64, n0 = blockIdx.y * 64;
    f32x4 c[4];
    #pragma unroll
    for (int jj = 0; jj < 4; ++jj) { f32x4 zv = {0.f, 0.f, 0.f, 0.f}; c[jj] = zv; }
    gemm64_core(ctxb + (size_t)m0 * 512, Wdb + (size_t)n0 * 512, sA, sB, threadIdx.x, c);
    const int tid = threadIdx.x, w = tid >> 6, lane = tid & 63, quad = lane >> 4, l15 = lane & 15;
    #pragma unroll
    for (int jj = 0; jj < 4; ++jj) {
        float bias = bd[n0 + jj * 16 + l15];
        #pragma unroll
        for (int r = 0; r < 4; ++r)
            out[(size_t)(m0 + w * 16 + quad * 4 + r) * 512 + n0 + jj * 16 + l15] = c[jj][r] + bias;
    }
}

// ---------------- flash attention v8: v7b structure, register budget restored (256,2) ----------------
// bid bits: [0..1]=quarter, [2]=b, [3..5]=h, [6..9]=qt. 16 S-tiles of 32 per block.
// NOTE: (256,3) forces ~170 VGPR budget but live state is ~250 (qf=128) -> scratch
// spill catastrophe (r8: WRITE 314MB, 41ms dispatch). Keep (256,2).
__global__ __launch_bounds__(256, 2) void flash_attn(const unsigned short* __restrict__ qb,
                                                     const unsigned short* __restrict__ kpack,
                                                     const unsigned short* __restrict__ vt,
                                                     const float* __restrict__ cb_all,
                                                     const float* __restrict__ mixing,
                                                     _Float16* __restrict__ Opart,
                                                     float* __restrict__ lpart) {
    __shared__ short sK[2][8192];     // 2 x 16 KB (one 32s x 256d chunk each)
    __shared__ short sV[2048];        // 4 KB, frag-major (4 frags x 512 shorts)
    const int bid = blockIdx.x;
    const int quarter = bid & 3, b = (bid >> 2) & 1, h = (bid >> 3) & 7, qt = bid >> 6;
    const int tid = threadIdx.x, w = tid >> 6, lane = tid & 63;
    const int l31 = lane & 31, hi = lane >> 5;
    const int q0 = qt * 128 + w * 32;
    const unsigned short* kbase = kpack + ((size_t)(b * 64 + quarter * 16)) * 32 * 512;
    const unsigned short* vtb = vt + ((size_t)(b * H_ + h) * 64) * (size_t)S_;
    const float* cbp = cb_all + (size_t)(b * H_ + h) * S_ + quarter * 512;
    const float* mixh = mixing + h * D_;

    // ---- Q B-frags (n=q=l31, k=d), mixing folded ----
    short8 qf[32];
    {
        const unsigned short* qrow = qb + ((size_t)(b * L_) + q0 + l31) * D_ + hi * 8;
        #pragma unroll
        for (int i = 0; i < 32; ++i) {
            ushort8 qv = *(const ushort8*)(qrow + i * 16);
            float4v ma = *(const float4v*)(mixh + i * 16 + hi * 8);
            float4v mb = *(const float4v*)(mixh + i * 16 + hi * 8 + 4);
            short8 ov;
            ov[0] = (short)f2bf(bf2f(qv[0]) * ma[0]);
            ov[1] = (short)f2bf(bf2f(qv[1]) * ma[1]);
            ov[2] = (short)f2bf(bf2f(qv[2]) * ma[2]);
            ov[3] = (short)f2bf(bf2f(qv[3]) * ma[3]);
            ov[4] = (short)f2bf(bf2f(qv[4]) * mb[0]);
            ov[5] = (short)f2bf(bf2f(qv[5]) * mb[1]);
            ov[6] = (short)f2bf(bf2f(qv[6]) * mb[2]);
            ov[7] = (short)f2bf(bf2f(qv[7]) * mb[3]);
            qf[i] = ov;
        }
    }

    f32x16 acco0, acco1;
    #pragma unroll
    for (int i = 0; i < 16; ++i) { acco0[i] = 0.f; acco1[i] = 0.f; }
    float lsum = 0.f;

    // ---- prologue: async-stage tile0 chunk0 -> buf0 ----
    #pragma unroll
    for (int ii = 0; ii < 4; ++ii)
        async16((char*)&sK[0][0] + w * 1024 + ii * 4096,
                (const char*)kbase + w * 1024 + ii * 4096 + (size_t)lane * 16);
    __syncthreads();

    for (int t = 0; t < 16; ++t) {
        f32x16 accsA, accsB;
        #pragma unroll
        for (int i = 0; i < 16; ++i) { accsA[i] = 0.f; accsB[i] = 0.f; }

        // ======== Phase A: issue chunk1 + V loads, compute chunk0 ========
        {
            const char* src = (const char*)(kbase + ((size_t)t * 32 + 16) * 512);
            #pragma unroll
            for (int ii = 0; ii < 4; ++ii)
                async16((char*)&sK[1][0] + w * 1024 + ii * 4096,
                        src + w * 1024 + ii * 4096 + (size_t)lane * 16);
            // V frag F=w: dhg=w>>1, sgi=w&1; lane (l31,hi) -> (dh=dhg*32+l31, s=t*32+sgi*16+hi*8)
            const unsigned short* gv = vtb + ((size_t)((w >> 1) * 32 + l31)) * (size_t)S_
                                       + quarter * 512 + t * 32 + (w & 1) * 16 + hi * 8;
            async16((char*)&sV[0] + w * 1024, gv);
        }
        #pragma unroll
        for (int f = 0; f < 16; ++f) {
            short8 a = *(const short8*)&sK[0][f * 512 + lane * 8];
            if (f & 1) accsB = __builtin_amdgcn_mfma_f32_32x32x16_bf16(a, qf[f], accsB, 0, 0, 0);
            else       accsA = __builtin_amdgcn_mfma_f32_32x32x16_bf16(a, qf[f], accsA, 0, 0, 0);
        }
        __syncthreads();   // drains async loads (vmcnt), protects buffers

        // ======== Phase B: issue next tile chunk0, compute chunk1, softmax, PV ========
        if (t < 15) {
            const char* src = (const char*)(kbase + ((size_t)(t + 1) * 32) * 512);
            #pragma unroll
            for (int ii = 0; ii < 4; ++ii)
                async16((char*)&sK[0][0] + w * 1024 + ii * 4096,
                        src + w * 1024 + ii * 4096 + (size_t)lane * 16);
        }
        #pragma unroll
        for (int f = 0; f < 16; ++f) {
            short8 a = *(const short8*)&sK[1][f * 512 + lane * 8];
            if (f & 1) accsB = __builtin_amdgcn_mfma_f32_32x32x16_bf16(a, qf[16 + f], accsB, 0, 0, 0);
            else       accsA = __builtin_amdgcn_mfma_f32_32x32x16_bf16(a, qf[16 + f], accsA, 0, 0, 0);
        }

        // ---- softmax numerator (no max; cb pre-scaled by 1/8) ----
        const int s0 = t * 32;
        float p[16];
        #pragma unroll
        for (int R = 0; R < 16; ++R) {
            const int cr = (R & 3) + 8 * (R >> 2);
            const int idx = s0 + cr - 4 * ((R >> 2) & 1);
            float cbA = cbp[idx];
            float cbB = cbp[idx + 8];
            float cbv = hi ? cbB : cbA;
            float pe = __expf((accsA[R] + accsB[R]) * 0.125f + cbv);
            p[R] = pe;
            lsum += pe;
        }
        // ---- pack P -> bf16 B-frags via +0x8000 (RN) + v_perm ----
        union { unsigned int u[4]; short8 s8; } P0, P1;
        #pragma unroll
        for (int j = 0; j < 4; ++j) {
            P0.u[j] = __builtin_amdgcn_perm(__float_as_uint(p[2 * j + 1]) + 0x8000u,
                                            __float_as_uint(p[2 * j]) + 0x8000u, 0x07060302u);
            P1.u[j] = __builtin_amdgcn_perm(__float_as_uint(p[8 + 2 * j + 1]) + 0x8000u,
                                            __float_as_uint(p[8 + 2 * j]) + 0x8000u, 0x07060302u);
        }
        // ---- O^T += V^T P^T ----
        {
            short8 av00 = *(const short8*)&sV[0 * 512 + lane * 8];
            short8 av01 = *(const short8*)&sV[1 * 512 + lane * 8];
            short8 av10 = *(const short8*)&sV[2 * 512 + lane * 8];
            short8 av11 = *(const short8*)&sV[3 * 512 + lane * 8];
            acco0 = __builtin_amdgcn_mfma_f32_32x32x16_bf16(av00, P0.s8, acco0, 0, 0, 0);
            acco0 = __builtin_amdgcn_mfma_f32_32x32x16_bf16(av01, P1.s8, acco0, 0, 0, 0);
            acco1 = __builtin_amdgcn_mfma_f32_32x32x16_bf16(av10, P0.s8, acco1, 0, 0, 0);
            acco1 = __builtin_amdgcn_mfma_f32_32x32x16_bf16(av11, P1.s8, acco1, 0, 0, 0);
        }
        __syncthreads();   // drains next-chunk0 load; protects sV/sK[0] for next tile
    }

    // ---- epilogue: lsum merge, fp16 O^T partials ----
    lsum += __shfl_xor(lsum, 32);
    if (hi == 0) lpart[(size_t)bid * 128 + w * 32 + l31] = lsum;
    #pragma unroll
    for (int R = 0; R < 16; ++R) {
        int dh = (R & 3) + 8 * (R >> 2) + 4 * hi;
        Opart[((size_t)bid * 64 + dh) * 128 + w * 32 + l31] = (_Float16)acco0[R];
        Opart[((size_t)bid * 64 + 32 + dh) * 128 + w * 32 + l31] = (_Float16)acco1[R];
    }
}

// ---------------- merge 4 split-S partials -> ctx (bf16) ----------------
__global__ __launch_bounds__(256) void merge_ctx(const _Float16* __restrict__ Opart,
                                                 const float* __restrict__ lpart,
                                                 unsigned short* __restrict__ ctxb) {
    int t = blockIdx.x * 256 + threadIdx.x;       // [0, 524288)
    int qq = t & 127, dh4 = (t >> 7) & 15, qt = (t >> 11) & 15, h = (t >> 15) & 7, b = t >> 18;
    int base = (qt << 6) | (h << 3) | (b << 2);   // flash bid with quarter=0
    float l = 0.f;
    #pragma unroll
    for (int p = 0; p < 4; ++p) l += lpart[(size_t)(base + p) * 128 + qq];
    float inv = 1.f / l;
    ushort4v o;
    #pragma unroll
    for (int e = 0; e < 4; ++e) {
        int dh = dh4 * 4 + e;
        float v = 0.f;
        #pragma unroll
        for (int p = 0; p < 4; ++p)
            v += (float)Opart[((size_t)(base + p) * 64 + dh) * 128 + qq];
        o[e] = f2bf(v * inv);
    }
    *(ushort4v*)(ctxb + ((size_t)(b * L_) + qt * 128 + qq) * 512 + h * 64 + dh4 * 4) = o;
}

extern "C" void kernel_launch(void* const* d_in, const int* in_sizes, int n_in,
                              void* d_out, int out_size, void* d_ws, size_t ws_size,
                              hipStream_t stream) {
    (void)in_sizes; (void)n_in; (void)out_size; (void)ws_size;
    const float* x      = (const float*)d_in[0];
    const float* Wq     = (const float*)d_in[1];
    const float* Wk     = (const float*)d_in[2];
    const float* Wv     = (const float*)d_in[3];
    const float* Wb     = (const float*)d_in[4];
    const float* mixing = (const float*)d_in[5];
    const float* Wd     = (const float*)d_in[6];
    const float* bd     = (const float*)d_in[7];
    float* out = (float*)d_out;

    char* ws = (char*)d_ws;
    const size_t MiB = 1048576;
    unsigned short* xb    = (unsigned short*)(ws);
    unsigned short* qb    = (unsigned short*)(ws + 4 * MiB);
    unsigned short* kpack = (unsigned short*)(ws + 8 * MiB);
    unsigned short* vt    = (unsigned short*)(ws + 12 * MiB);
    unsigned short* ctxb  = (unsigned short*)(ws + 16 * MiB);
    unsigned short* Wqb   = (unsigned short*)(ws + 20 * MiB);
    unsigned short* Wkb   = (unsigned short*)(ws + 20 * MiB + 512 * 1024);
    unsigned short* Wvb   = (unsigned short*)(ws + 21 * MiB);
    unsigned short* Wdb   = (unsigned short*)(ws + 21 * MiB + 512 * 1024);
    float* cbuf           = (float*)(ws + 22 * MiB);            // 128 KB
    float* lpart          = (float*)(ws + 23 * MiB);            // 512 KB
    _Float16* Opart       = (_Float16*)(ws + 24 * MiB);         // 16.78 MB

    cvt_all<<<3072, 256, 0, stream>>>(x, Wq, Wk, Wv, Wd, xb, Wqb, Wkb, Wvb, Wdb);
    gemm_qkv<<<dim3(64, 8, 3), 256, 0, stream>>>(xb, Wqb, Wkb, Wvb, qb, kpack, vt);
    cb_kernel<<<1024, 256, 0, stream>>>(x, Wb, cbuf);
    flash_attn<<<1024, 256, 0, stream>>>(qb, kpack, vt, cbuf, mixing, Opart, lpart);
    merge_ctx<<<2048, 256, 0, stream>>>(Opart, lpart, ctxb);
    gemm_out<<<dim3(64, 8), 256, 0, stream>>>(ctxb, Wdb, bd, out);
}

// Round 10
// 230.815 us; speedup vs baseline: 1.9452x; 1.1376x over previous
//
#include <hip/hip_runtime.h>

#define B_ 2
#define L_ 2048
#define D_ 512
#define H_ 8
#define S_ 2048

typedef __attribute__((ext_vector_type(8))) short short8;
typedef __attribute__((ext_vector_type(8))) unsigned short ushort8;
typedef __attribute__((ext_vector_type(4))) unsigned short ushort4v;
typedef __attribute__((ext_vector_type(4))) float f32x4;
typedef __attribute__((ext_vector_type(16))) float f32x16;
typedef __attribute__((ext_vector_type(4))) float float4v;

__device__ __forceinline__ unsigned short f2bf(float f) {
    unsigned u = __float_as_uint(f);
    u += 0x7FFF + ((u >> 16) & 1);   // RTNE
    return (unsigned short)(u >> 16);
}
__device__ __forceinline__ float bf2f(unsigned short s) {
    return __uint_as_float(((unsigned)s) << 16);
}
// swap bits 2 and 3 (self-inverse) — K-row permutation making S^T C-regs = PV B-frag order
__device__ __forceinline__ int swap23(int x) {
    return (x & ~12) | ((x & 4) << 1) | ((x & 8) >> 1);
}
// async global->LDS, 16B per lane; LDS dest = uniform base + lane*16
__device__ __forceinline__ void async16(void* lds, const void* g) {
    __builtin_amdgcn_global_load_lds(
        (const __attribute__((address_space(1))) void*)(g),
        (__attribute__((address_space(3))) void*)(lds), 16, 0, 0);
}

// ---------------- fused fp32->bf16 converts: x (524288 f4) + 4 weights (65536 f4 each) ----------------
__global__ __launch_bounds__(256) void cvt_all(const float* __restrict__ x,
                                               const float* __restrict__ w0, const float* __restrict__ w1,
                                               const float* __restrict__ w2, const float* __restrict__ w3,
                                               unsigned short* __restrict__ xb,
                                               unsigned short* __restrict__ d0, unsigned short* __restrict__ d1,
                                               unsigned short* __restrict__ d2, unsigned short* __restrict__ d3) {
    int i = blockIdx.x * 256 + threadIdx.x;   // [0, 786432)
    const float* s;
    unsigned short* d;
    int idx;
    if (i < 524288) { s = x; d = xb; idx = i; }
    else {
        int off = i - 524288;                  // [0, 262144): 4 weights x 65536 float4
        int wsel = off >> 16; idx = off & 65535;
        s = (wsel == 0) ? w0 : (wsel == 1) ? w1 : (wsel == 2) ? w2 : w3;
        d = (wsel == 0) ? d0 : (wsel == 1) ? d1 : (wsel == 2) ? d2 : d3;
    }
    float4v v = *(const float4v*)(s + (size_t)idx * 4);
    ushort4v o;
    o[0] = f2bf(v[0]); o[1] = f2bf(v[1]); o[2] = f2bf(v[2]); o[3] = f2bf(v[3]);
    *(ushort4v*)(d + (size_t)idx * 4) = o;
}

// ---------------- content bias (PRE-SCALED by 1/8): cb'[b,h,s] = dot(x,Wb)/8 ----------------
__global__ __launch_bounds__(256) void cb_kernel(const float* __restrict__ x,
                                                 const float* __restrict__ Wb,
                                                 float* __restrict__ cb) {
    const int tid = threadIdx.x, w = tid >> 6, lane = tid & 63;
    const int row = blockIdx.x * 4 + w;            // [0, 4096)
    const int h = lane >> 3, seg = lane & 7;
    const float* xp = x + (size_t)row * 512 + seg * 64;
    const float* wp = Wb + (size_t)h * 512 + seg * 64;
    float acc = 0.f;
    #pragma unroll
    for (int j = 0; j < 16; ++j) {
        float4v xv = *(const float4v*)(xp + j * 4);
        float4v wv = *(const float4v*)(wp + j * 4);
        acc += xv[0] * wv[0] + xv[1] * wv[1] + xv[2] * wv[2] + xv[3] * wv[3];
    }
    acc += __shfl_xor(acc, 1);
    acc += __shfl_xor(acc, 2);
    acc += __shfl_xor(acc, 4);
    if (seg == 0) {
        int b = row >> 11, s = row & 2047;
        cb[((size_t)(b * H_ + h)) * S_ + s] = acc * 0.125f;
    }
}

// ---------------- 128x128-tile GEMM core: 4 waves in 2x2, each 64x64 quadrant ----------------
__device__ __forceinline__ void gemm128_core(const unsigned short* __restrict__ Ap,
                                             const unsigned short* __restrict__ Bp,
                                             short* sA, short* sB, int tid, f32x4 c[4][4]) {
    const int w = tid >> 6, lane = tid & 63, quad = lane >> 4, l15 = lane & 15;
    const int wm = (w >> 1) * 64, wn = (w & 1) * 64;
    for (int kc = 0; kc < 8; ++kc) {
        __syncthreads();
        #pragma unroll
        for (int j = 0; j < 4; ++j) {
            int i = tid + j * 256;          // 1024 slots = 128 rows x 64 cols / 8
            int row = i >> 3, seg = i & 7;
            *(ushort8*)&sA[row * 72 + seg * 8] = *(const ushort8*)(Ap + (size_t)row * 512 + kc * 64 + seg * 8);
            *(ushort8*)&sB[row * 72 + seg * 8] = *(const ushort8*)(Bp + (size_t)row * 512 + kc * 64 + seg * 8);
        }
        __syncthreads();
        #pragma unroll
        for (int ks = 0; ks < 2; ++ks) {
            short8 a[4], b[4];
            #pragma unroll
            for (int ii = 0; ii < 4; ++ii)
                a[ii] = *(const short8*)&sA[(wm + ii * 16 + l15) * 72 + ks * 32 + quad * 8];
            #pragma unroll
            for (int jj = 0; jj < 4; ++jj)
                b[jj] = *(const short8*)&sB[(wn + jj * 16 + l15) * 72 + ks * 32 + quad * 8];
            #pragma unroll
            for (int ii = 0; ii < 4; ++ii)
                #pragma unroll
                for (int jj = 0; jj < 4; ++jj)
                    c[ii][jj] = __builtin_amdgcn_mfma_f32_16x16x32_bf16(a[ii], b[jj], c[ii][jj], 0, 0, 0);
        }
    }
}

// ---------------- q,k,v projections (128x128 tiles) ----------------
// q: row-major bf16.
// K: A-frag packed for 32x32x16, rows sigma-permuted:
//    addr = ((b*64 + (s>>5))*32 + (d>>4))*512 + ((d>>3)&1)*256 + swap23(s&31)*8 + (d&7)
// V: transposed row-major vt[b][h][dh][s]
__global__ __launch_bounds__(256) void gemm_qkv(const unsigned short* __restrict__ xb,
                                                const unsigned short* __restrict__ Wqb,
                                                const unsigned short* __restrict__ Wkb,
                                                const unsigned short* __restrict__ Wvb,
                                                unsigned short* __restrict__ qb,
                                                unsigned short* __restrict__ kpack,
                                                unsigned short* __restrict__ vt) {
    __shared__ short sA[128 * 72];
    __shared__ short sB[128 * 72];
    const int m0 = blockIdx.x * 128, n0 = blockIdx.y * 128, z = blockIdx.z;
    const unsigned short* Bsel = (z == 0) ? Wqb : ((z == 1) ? Wkb : Wvb);
    f32x4 c[4][4];
    #pragma unroll
    for (int ii = 0; ii < 4; ++ii)
        #pragma unroll
        for (int jj = 0; jj < 4; ++jj) { f32x4 zv = {0.f, 0.f, 0.f, 0.f}; c[ii][jj] = zv; }
    gemm128_core(xb + (size_t)m0 * 512, Bsel + (size_t)n0 * 512, sA, sB, threadIdx.x, c);
    const int tid = threadIdx.x, w = tid >> 6, lane = tid & 63, quad = lane >> 4, l15 = lane & 15;
    const int wm = (w >> 1) * 64, wn = (w & 1) * 64;
    #pragma unroll
    for (int ii = 0; ii < 4; ++ii) {
        const int mb = m0 + wm + ii * 16 + quad * 4;
        const int bb = mb >> 11;
        if (z == 0) {
            #pragma unroll
            for (int jj = 0; jj < 4; ++jj) {
                int ncol = n0 + wn + jj * 16 + l15;
                #pragma unroll
                for (int r = 0; r < 4; ++r)
                    qb[(size_t)(mb + r) * 512 + ncol] = f2bf(c[ii][jj][r]);
            }
        } else if (z == 1) {
            #pragma unroll
            for (int jj = 0; jj < 4; ++jj) {
                int d = n0 + wn + jj * 16 + l15;
                int f = d >> 4, hid = (d >> 3) & 1, jq = d & 7;
                #pragma unroll
                for (int r = 0; r < 4; ++r) {
                    int s = (mb + r) & 2047;
                    int t = s >> 5, rr = swap23(s & 31);
                    kpack[(((size_t)(bb * 64 + t)) * 32 + f) * 512 + hid * 256 + rr * 8 + jq]
                        = f2bf(c[ii][jj][r]);
                }
            }
        } else {
            const int hh = (n0 + wn) >> 6;
            const int s = mb & 2047;
            #pragma unroll
            for (int jj = 0; jj < 4; ++jj) {
                int dh = jj * 16 + l15;
                ushort4v o;
                o[0] = f2bf(c[ii][jj][0]); o[1] = f2bf(c[ii][jj][1]);
                o[2] = f2bf(c[ii][jj][2]); o[3] = f2bf(c[ii][jj][3]);
                *(ushort4v*)(vt + (((size_t)(bb * H_ + hh) * 64 + dh) * S_ + s)) = o;
            }
        }
    }
}

// ---------------- output projection (128x128 tiles, fp32 out + bias) ----------------
__global__ __launch_bounds__(256) void gemm_out(const unsigned short* __restrict__ ctxb,
                                                const unsigned short* __restrict__ Wdb,
                                                const float* __restrict__ bd,
                                                float* __restrict__ out) {
    __shared__ short sA[128 * 72];
    __shared__ short sB[128 * 72];
    const int m0 = blockIdx.x * 128, n0 = blockIdx.y * 128;
    f32x4 c[4][4];
    #pragma unroll
    for (int ii = 0; ii < 4; ++ii)
        #pragma unroll
        for (int jj = 0; jj < 4; ++jj) { f32x4 zv = {0.f, 0.f, 0.f, 0.f}; c[ii][jj] = zv; }
    gemm128_core(ctxb + (size_t)m0 * 512, Wdb + (size_t)n0 * 512, sA, sB, threadIdx.x, c);
    const int tid = threadIdx.x, w = tid >> 6, lane = tid & 63, quad = lane >> 4, l15 = lane & 15;
    const int wm = (w >> 1) * 64, wn = (w & 1) * 64;
    #pragma unroll
    for (int ii = 0; ii < 4; ++ii) {
        const int mb = m0 + wm + ii * 16 + quad * 4;
        #pragma unroll
        for (int jj = 0; jj < 4; ++jj) {
            int ncol = n0 + wn + jj * 16 + l15;
            float bias = bd[ncol];
            #pragma unroll
            for (int r = 0; r < 4; ++r)
                out[(size_t)(mb + r) * 512 + ncol] = c[ii][jj][r] + bias;
        }
    }
}

// ---------------- flash attention v9: split-S x2 + async staging (r6 shape + r9 micro-opts) ----------------
// bid bits: [0]=half, [1]=b, [2..4]=h, [5..8]=qt. 32 S-tiles of 32 per block.
// NOTE: (256,3) forces ~170 VGPR budget but live state ~250 (qf=128) -> scratch spill
// (r8: 41ms). Keep (256,2). Split x4 regressed (r9: prologue amortization halved).
__global__ __launch_bounds__(256, 2) void flash_attn(const unsigned short* __restrict__ qb,
                                                     const unsigned short* __restrict__ kpack,
                                                     const unsigned short* __restrict__ vt,
                                                     const float* __restrict__ cb_all,
                                                     const float* __restrict__ mixing,
                                                     _Float16* __restrict__ Opart,
                                                     float* __restrict__ lpart) {
    __shared__ short sK[2][8192];     // 2 x 16 KB (one 32s x 256d chunk each)
    __shared__ short sV[2048];        // 4 KB, frag-major (4 frags x 512 shorts)
    const int bid = blockIdx.x;
    const int half = bid & 1, b = (bid >> 1) & 1, h = (bid >> 2) & 7, qt = bid >> 5;
    const int tid = threadIdx.x, w = tid >> 6, lane = tid & 63;
    const int l31 = lane & 31, hi = lane >> 5;
    const int q0 = qt * 128 + w * 32;
    const unsigned short* kbase = kpack + ((size_t)(b * 64 + half * 32)) * 32 * 512;
    const unsigned short* vtb = vt + ((size_t)(b * H_ + h) * 64) * (size_t)S_;
    const float* cbp = cb_all + (size_t)(b * H_ + h) * S_ + half * 1024;
    const float* mixh = mixing + h * D_;

    // ---- Q B-frags (n=q=l31, k=d), mixing folded ----
    short8 qf[32];
    {
        const unsigned short* qrow = qb + ((size_t)(b * L_) + q0 + l31) * D_ + hi * 8;
        #pragma unroll
        for (int i = 0; i < 32; ++i) {
            ushort8 qv = *(const ushort8*)(qrow + i * 16);
            float4v ma = *(const float4v*)(mixh + i * 16 + hi * 8);
            float4v mb = *(const float4v*)(mixh + i * 16 + hi * 8 + 4);
            short8 ov;
            ov[0] = (short)f2bf(bf2f(qv[0]) * ma[0]);
            ov[1] = (short)f2bf(bf2f(qv[1]) * ma[1]);
            ov[2] = (short)f2bf(bf2f(qv[2]) * ma[2]);
            ov[3] = (short)f2bf(bf2f(qv[3]) * ma[3]);
            ov[4] = (short)f2bf(bf2f(qv[4]) * mb[0]);
            ov[5] = (short)f2bf(bf2f(qv[5]) * mb[1]);
            ov[6] = (short)f2bf(bf2f(qv[6]) * mb[2]);
            ov[7] = (short)f2bf(bf2f(qv[7]) * mb[3]);
            qf[i] = ov;
        }
    }

    f32x16 acco0, acco1;
    #pragma unroll
    for (int i = 0; i < 16; ++i) { acco0[i] = 0.f; acco1[i] = 0.f; }
    float lsum = 0.f;

    // ---- prologue: async-stage tile0 chunk0 -> buf0 ----
    #pragma unroll
    for (int ii = 0; ii < 4; ++ii)
        async16((char*)&sK[0][0] + w * 1024 + ii * 4096,
                (const char*)kbase + w * 1024 + ii * 4096 + (size_t)lane * 16);
    __syncthreads();

    for (int t = 0; t < 32; ++t) {
        f32x16 accsA, accsB;
        #pragma unroll
        for (int i = 0; i < 16; ++i) { accsA[i] = 0.f; accsB[i] = 0.f; }

        // ======== Phase A: issue chunk1 + V loads, compute chunk0 ========
        {
            const char* src = (const char*)(kbase + ((size_t)t * 32 + 16) * 512);
            #pragma unroll
            for (int ii = 0; ii < 4; ++ii)
                async16((char*)&sK[1][0] + w * 1024 + ii * 4096,
                        src + w * 1024 + ii * 4096 + (size_t)lane * 16);
            // V frag F=w: dhg=w>>1, sgi=w&1; lane (l31,hi) -> (dh=dhg*32+l31, s=t*32+sgi*16+hi*8)
            const unsigned short* gv = vtb + ((size_t)((w >> 1) * 32 + l31)) * (size_t)S_
                                       + half * 1024 + t * 32 + (w & 1) * 16 + hi * 8;
            async16((char*)&sV[0] + w * 1024, gv);
        }
        #pragma unroll
        for (int f = 0; f < 16; ++f) {
            short8 a = *(const short8*)&sK[0][f * 512 + lane * 8];
            if (f & 1) accsB = __builtin_amdgcn_mfma_f32_32x32x16_bf16(a, qf[f], accsB, 0, 0, 0);
            else       accsA = __builtin_amdgcn_mfma_f32_32x32x16_bf16(a, qf[f], accsA, 0, 0, 0);
        }
        __syncthreads();   // drains async loads (vmcnt), protects buffers

        // ======== Phase B: issue next tile chunk0, compute chunk1, softmax, PV ========
        if (t < 31) {
            const char* src = (const char*)(kbase + ((size_t)(t + 1) * 32) * 512);
            #pragma unroll
            for (int ii = 0; ii < 4; ++ii)
                async16((char*)&sK[0][0] + w * 1024 + ii * 4096,
                        src + w * 1024 + ii * 4096 + (size_t)lane * 16);
        }
        #pragma unroll
        for (int f = 0; f < 16; ++f) {
            short8 a = *(const short8*)&sK[1][f * 512 + lane * 8];
            if (f & 1) accsB = __builtin_amdgcn_mfma_f32_32x32x16_bf16(a, qf[16 + f], accsB, 0, 0, 0);
            else       accsA = __builtin_amdgcn_mfma_f32_32x32x16_bf16(a, qf[16 + f], accsA, 0, 0, 0);
        }

        // ---- softmax numerator (no max; cb pre-scaled by 1/8) ----
        const int s0 = t * 32;
        float p[16];
        #pragma unroll
        for (int R = 0; R < 16; ++R) {
            const int cr = (R & 3) + 8 * (R >> 2);
            const int idx = s0 + cr - 4 * ((R >> 2) & 1);
            float cbA = cbp[idx];
            float cbB = cbp[idx + 8];
            float cbv = hi ? cbB : cbA;
            float pe = __expf((accsA[R] + accsB[R]) * 0.125f + cbv);
            p[R] = pe;
            lsum += pe;
        }
        // ---- pack P -> bf16 B-frags via +0x8000 (RN) + v_perm ----
        union { unsigned int u[4]; short8 s8; } P0, P1;
        #pragma unroll
        for (int j = 0; j < 4; ++j) {
            P0.u[j] = __builtin_amdgcn_perm(__float_as_uint(p[2 * j + 1]) + 0x8000u,
                                            __float_as_uint(p[2 * j]) + 0x8000u, 0x07060302u);
            P1.u[j] = __builtin_amdgcn_perm(__float_as_uint(p[8 + 2 * j + 1]) + 0x8000u,
                                            __float_as_uint(p[8 + 2 * j]) + 0x8000u, 0x07060302u);
        }
        // ---- O^T += V^T P^T ----
        {
            short8 av00 = *(const short8*)&sV[0 * 512 + lane * 8];
            short8 av01 = *(const short8*)&sV[1 * 512 + lane * 8];
            short8 av10 = *(const short8*)&sV[2 * 512 + lane * 8];
            short8 av11 = *(const short8*)&sV[3 * 512 + lane * 8];
            acco0 = __builtin_amdgcn_mfma_f32_32x32x16_bf16(av00, P0.s8, acco0, 0, 0, 0);
            acco0 = __builtin_amdgcn_mfma_f32_32x32x16_bf16(av01, P1.s8, acco0, 0, 0, 0);
            acco1 = __builtin_amdgcn_mfma_f32_32x32x16_bf16(av10, P0.s8, acco1, 0, 0, 0);
            acco1 = __builtin_amdgcn_mfma_f32_32x32x16_bf16(av11, P1.s8, acco1, 0, 0, 0);
        }
        __syncthreads();   // drains next-chunk0 load; protects sV/sK[0] for next tile
    }

    // ---- epilogue: lsum merge, fp16 O^T partials ----
    lsum += __shfl_xor(lsum, 32);
    if (hi == 0) lpart[(size_t)bid * 128 + w * 32 + l31] = lsum;
    #pragma unroll
    for (int R = 0; R < 16; ++R) {
        int dh = (R & 3) + 8 * (R >> 2) + 4 * hi;
        Opart[((size_t)bid * 64 + dh) * 128 + w * 32 + l31] = (_Float16)acco0[R];
        Opart[((size_t)bid * 64 + 32 + dh) * 128 + w * 32 + l31] = (_Float16)acco1[R];
    }
}

// ---------------- merge 2 split-S partials -> ctx (bf16) ----------------
__global__ __launch_bounds__(256) void merge_ctx(const _Float16* __restrict__ Opart,
                                                 const float* __restrict__ lpart,
                                                 unsigned short* __restrict__ ctxb) {
    int t = blockIdx.x * 256 + threadIdx.x;       // [0, 524288)
    int qq = t & 127, dh4 = (t >> 7) & 15, qt = (t >> 11) & 15, h = (t >> 15) & 7, b = t >> 18;
    int base = (qt << 5) | (h << 2) | (b << 1);   // flash bid with half=0
    float l = lpart[(size_t)base * 128 + qq] + lpart[(size_t)(base + 1) * 128 + qq];
    float inv = 1.f / l;
    ushort4v o;
    #pragma unroll
    for (int e = 0; e < 4; ++e) {
        int dh = dh4 * 4 + e;
        float v = (float)Opart[((size_t)base * 64 + dh) * 128 + qq]
                + (float)Opart[((size_t)(base + 1) * 64 + dh) * 128 + qq];
        o[e] = f2bf(v * inv);
    }
    *(ushort4v*)(ctxb + ((size_t)(b * L_) + qt * 128 + qq) * 512 + h * 64 + dh4 * 4) = o;
}

extern "C" void kernel_launch(void* const* d_in, const int* in_sizes, int n_in,
                              void* d_out, int out_size, void* d_ws, size_t ws_size,
                              hipStream_t stream) {
    (void)in_sizes; (void)n_in; (void)out_size; (void)ws_size;
    const float* x      = (const float*)d_in[0];
    const float* Wq     = (const float*)d_in[1];
    const float* Wk     = (const float*)d_in[2];
    const float* Wv     = (const float*)d_in[3];
    const float* Wb     = (const float*)d_in[4];
    const float* mixing = (const float*)d_in[5];
    const float* Wd     = (const float*)d_in[6];
    const float* bd     = (const float*)d_in[7];
    float* out = (float*)d_out;

    char* ws = (char*)d_ws;
    const size_t MiB = 1048576;
    unsigned short* xb    = (unsigned short*)(ws);
    unsigned short* qb    = (unsigned short*)(ws + 4 * MiB);
    unsigned short* kpack = (unsigned short*)(ws + 8 * MiB);
    unsigned short* vt    = (unsigned short*)(ws + 12 * MiB);
    unsigned short* ctxb  = (unsigned short*)(ws + 16 * MiB);
    unsigned short* Wqb   = (unsigned short*)(ws + 20 * MiB);
    unsigned short* Wkb   = (unsigned short*)(ws + 20 * MiB + 512 * 1024);
    unsigned short* Wvb   = (unsigned short*)(ws + 21 * MiB);
    unsigned short* Wdb   = (unsigned short*)(ws + 21 * MiB + 512 * 1024);
    float* cbuf           = (float*)(ws + 22 * MiB);            // 128 KB
    float* lpart          = (float*)(ws + 23 * MiB);            // 256 KB
    _Float16* Opart       = (_Float16*)(ws + 24 * MiB);         // 8.4 MB

    cvt_all<<<3072, 256, 0, stream>>>(x, Wq, Wk, Wv, Wd, xb, Wqb, Wkb, Wvb, Wdb);
    gemm_qkv<<<dim3(32, 4, 3), 256, 0, stream>>>(xb, Wqb, Wkb, Wvb, qb, kpack, vt);
    cb_kernel<<<1024, 256, 0, stream>>>(x, Wb, cbuf);
    flash_attn<<<512, 256, 0, stream>>>(qb, kpack, vt, cbuf, mixing, Opart, lpart);
    merge_ctx<<<2048, 256, 0, stream>>>(Opart, lpart, ctxb);
    gemm_out<<<dim3(32, 4), 256, 0, stream>>>(ctxb, Wdb, bd, out);
}